// Round 1
// baseline (607.889 us; speedup 1.0000x reference)
//
#include <hip/hip_runtime.h>

typedef __attribute__((ext_vector_type(8))) short short8;
typedef __attribute__((ext_vector_type(4))) float f32x4;
typedef unsigned short ushort_t;
typedef unsigned int uint_t;

#define BM 128
#define BN 128
#define BK 32
#define LDP 40   // padded LDS row stride in ushorts (80 B, multiple of 16 B)

__device__ __forceinline__ ushort_t f2bf(float f) {
    uint_t u = __float_as_uint(f);
    uint_t r = (u + 0x7fffu + ((u >> 16) & 1u)) >> 16;   // RNE
    return (ushort_t)r;
}
__device__ __forceinline__ float bf2f(ushort_t b) {
    return __uint_as_float(((uint_t)b) << 16);
}

__global__ __launch_bounds__(256, 2)
void q4_gemm_kernel(const float* __restrict__ X,
                    const int* __restrict__ WP,
                    const float* __restrict__ S,
                    const float* __restrict__ Z,
                    const float* __restrict__ Bi,
                    float* __restrict__ C,
                    int M, int N, int K, int NG)
{
    __shared__ __align__(16) ushort_t sa_hi[BM][LDP];
    __shared__ __align__(16) ushort_t sa_lo[BM][LDP];
    __shared__ __align__(16) ushort_t sb_hi[BN][LDP];
    __shared__ __align__(16) ushort_t sb_lo[BN][LDP];

    const int nbx = N / BN;
    const int bx = blockIdx.x % nbx;
    const int by = blockIdx.x / nbx;
    const int brow = by * BM;
    const int bcol = bx * BN;

    const int t = threadIdx.x;
    const int lane = t & 63;
    const int wid = t >> 6;
    const int wr = wid >> 1;      // 0..1
    const int wc = wid & 1;       // 0..1

    // X staging: 8 float4 per 32-float row; lanes 0-7 cover one full row (128B)
    const int xc4 = t & 7;        // float4 index within k-tile
    const int xr0 = t >> 3;       // 0..31, 4 passes of +32
    // W staging: 2 threads per n-row, 8 packed int32 (16 weights) each
    const int wrow  = t >> 1;     // 0..127
    const int whalf = t & 1;

    const int Kh = K >> 1;

    f32x4 acc[4][4];
    #pragma unroll
    for (int m = 0; m < 4; ++m)
        #pragma unroll
        for (int n = 0; n < 4; ++n)
            acc[m][n] = (f32x4)0.f;

    const int fr = lane & 15;          // A-row / B-col within 16
    const int k8 = (lane >> 4) << 3;   // k offset 0/8/16/24

    const int nkt = K / BK;
    for (int kt = 0; kt < nkt; ++kt) {
        // ---------- stage X tile (fp32 -> bf16 hi/lo) ----------
        #pragma unroll
        for (int p = 0; p < 4; ++p) {
            const int r = xr0 + p * 32;
            const float4 v = *(const float4*)&X[(brow + r) * K + kt * BK + xc4 * 4];
            ushort_t h[4], l[4];
            h[0] = f2bf(v.x); l[0] = f2bf(v.x - bf2f(h[0]));
            h[1] = f2bf(v.y); l[1] = f2bf(v.y - bf2f(h[1]));
            h[2] = f2bf(v.z); l[2] = f2bf(v.z - bf2f(h[2]));
            h[3] = f2bf(v.w); l[3] = f2bf(v.w - bf2f(h[3]));
            *(ushort4*)&sa_hi[r][xc4 * 4] = *(ushort4*)&h[0];
            *(ushort4*)&sa_lo[r][xc4 * 4] = *(ushort4*)&l[0];
        }

        // ---------- stage W tile (unpack + dequant -> bf16 hi/lo) ----------
        {
            const int n = bcol + wrow;
            const float s   = S[n * NG + kt];   // BK == GROUP == 32, k-aligned -> group = kt
            const float z   = Z[n * NG + kt];
            const float nzs = -z * s;
            const int4* pp = (const int4*)&WP[n * Kh + kt * 16 + whalf * 8];
            const int4 p0 = pp[0];
            const int4 p1 = pp[1];
            const int vals[8] = {p0.x, p0.y, p0.z, p0.w, p1.x, p1.y, p1.z, p1.w};
            __align__(16) ushort_t hi[16];
            __align__(16) ushort_t lo[16];
            #pragma unroll
            for (int j = 0; j < 8; ++j) {
                const int v = vals[j];
                const float w0 = fmaf((float)(v & 15),        s, nzs);
                const float w1 = fmaf((float)((v >> 4) & 15), s, nzs);
                hi[2*j]   = f2bf(w0); lo[2*j]   = f2bf(w0 - bf2f(hi[2*j]));
                hi[2*j+1] = f2bf(w1); lo[2*j+1] = f2bf(w1 - bf2f(hi[2*j+1]));
            }
            *(ushort4*)&sb_hi[wrow][whalf * 16 + 0]  = *(ushort4*)&hi[0];
            *(ushort4*)&sb_hi[wrow][whalf * 16 + 4]  = *(ushort4*)&hi[4];
            *(ushort4*)&sb_hi[wrow][whalf * 16 + 8]  = *(ushort4*)&hi[8];
            *(ushort4*)&sb_hi[wrow][whalf * 16 + 12] = *(ushort4*)&hi[12];
            *(ushort4*)&sb_lo[wrow][whalf * 16 + 0]  = *(ushort4*)&lo[0];
            *(ushort4*)&sb_lo[wrow][whalf * 16 + 4]  = *(ushort4*)&lo[4];
            *(ushort4*)&sb_lo[wrow][whalf * 16 + 8]  = *(ushort4*)&lo[8];
            *(ushort4*)&sb_lo[wrow][whalf * 16 + 12] = *(ushort4*)&lo[12];
        }

        __syncthreads();

        // ---------- fragments + MFMA ----------
        short8 ah[4], al[4], bh[4], bl[4];
        #pragma unroll
        for (int m = 0; m < 4; ++m) {
            ah[m] = *(const short8*)&sa_hi[wr * 64 + m * 16 + fr][k8];
            al[m] = *(const short8*)&sa_lo[wr * 64 + m * 16 + fr][k8];
        }
        #pragma unroll
        for (int n = 0; n < 4; ++n) {
            bh[n] = *(const short8*)&sb_hi[wc * 64 + n * 16 + fr][k8];
            bl[n] = *(const short8*)&sb_lo[wc * 64 + n * 16 + fr][k8];
        }
        #pragma unroll
        for (int m = 0; m < 4; ++m)
            #pragma unroll
            for (int n = 0; n < 4; ++n) {
                acc[m][n] = __builtin_amdgcn_mfma_f32_16x16x32_bf16(ah[m], bh[n], acc[m][n], 0, 0, 0);
                acc[m][n] = __builtin_amdgcn_mfma_f32_16x16x32_bf16(ah[m], bl[n], acc[m][n], 0, 0, 0);
                acc[m][n] = __builtin_amdgcn_mfma_f32_16x16x32_bf16(al[m], bh[n], acc[m][n], 0, 0, 0);
            }

        __syncthreads();
    }

    // ---------- epilogue: C = acc + bias ----------
    const int row4 = (lane >> 4) << 2;   // C/D: col = lane&15, row = (lane>>4)*4 + i  [m89]
    const int col  = lane & 15;
    #pragma unroll
    for (int n = 0; n < 4; ++n) {
        const int gc = bcol + wc * 64 + n * 16 + col;
        const float b = Bi[gc];
        #pragma unroll
        for (int m = 0; m < 4; ++m) {
            const int gr = brow + wr * 64 + m * 16 + row4;
            #pragma unroll
            for (int i = 0; i < 4; ++i) {
                C[(gr + i) * N + gc] = acc[m][n][i] + b;
            }
        }
    }
}

extern "C" void kernel_launch(void* const* d_in, const int* in_sizes, int n_in,
                              void* d_out, int out_size, void* d_ws, size_t ws_size,
                              hipStream_t stream)
{
    const float* X  = (const float*)d_in[0];
    const int*   WP = (const int*)d_in[1];
    const float* S  = (const float*)d_in[2];
    const float* Z  = (const float*)d_in[3];
    const float* Bi = (const float*)d_in[4];
    float* C = (float*)d_out;

    const int O  = in_sizes[4];            // 4096
    const int NG = in_sizes[2] / O;        // 128 groups
    const int K  = NG * 32;                // 4096
    const int M  = in_sizes[0] / K;        // 4096 (= B*S)

    dim3 grid((M / BM) * (O / BN));
    q4_gemm_kernel<<<grid, 256, 0, stream>>>(X, WP, S, Z, Bi, C, M, O, K, NG);
}

// Round 2
// 446.764 us; speedup vs baseline: 1.3606x; 1.3606x over previous
//
#include <hip/hip_runtime.h>

typedef __attribute__((ext_vector_type(8))) short short8;
typedef __attribute__((ext_vector_type(4))) float f32x4;
typedef unsigned short u16;
typedef unsigned int u32;

#define BM 128
#define BN 128
#define BK 32
#define LDP 40   // fused-fallback padded stride

__device__ __forceinline__ u16 f2bf_rne(float f) {
    u32 u = __float_as_uint(f);
    return (u16)((u + 0x7fffu + ((u >> 16) & 1u)) >> 16);
}
__device__ __forceinline__ float bf2f(u16 b) { return __uint_as_float(((u32)b) << 16); }

// ---------------- prep kernels (decomposed path) ----------------

// One thread per (o, group): unpack 32 nibbles, dequant, write 32 bf16 (64 B).
__global__ __launch_bounds__(256)
void prep_w(const int* __restrict__ WP, const float* __restrict__ S,
            const float* __restrict__ Z, u16* __restrict__ Wd, int NG)
{
    const int tid = blockIdx.x * blockDim.x + threadIdx.x;
    const int o = tid / NG, g = tid % NG;
    const float s = S[o * NG + g];
    const float nzs = -Z[o * NG + g] * s;
    const int4* p = (const int4*)&WP[(size_t)(o * NG + g) * 16];
    __align__(16) u16 out[32];
    #pragma unroll
    for (int q4 = 0; q4 < 4; ++q4) {
        const int4 v4 = p[q4];
        const int vv[4] = {v4.x, v4.y, v4.z, v4.w};
        #pragma unroll
        for (int j = 0; j < 4; ++j) {
            const int v = vv[j];
            out[(q4 * 4 + j) * 2]     = f2bf_rne(fmaf((float)(v & 15), s, nzs));
            out[(q4 * 4 + j) * 2 + 1] = f2bf_rne(fmaf((float)((v >> 4) & 15), s, nzs));
        }
    }
    uint4* dst = (uint4*)&Wd[(size_t)tid * 32];
    const uint4* src = (const uint4*)out;
    dst[0] = src[0]; dst[1] = src[1]; dst[2] = src[2]; dst[3] = src[3];
}

// One thread per float4: X -> bf16 hi (RNE) + bf16 lo (trunc of exact residual).
__global__ __launch_bounds__(256)
void prep_x(const float* __restrict__ X, u16* __restrict__ Xh, u16* __restrict__ Xl)
{
    const int tid = blockIdx.x * blockDim.x + threadIdx.x;
    const float4 v = ((const float4*)X)[tid];
    const float f[4] = {v.x, v.y, v.z, v.w};
    __align__(8) u16 h[4], l[4];
    #pragma unroll
    for (int j = 0; j < 4; ++j) {
        h[j] = f2bf_rne(f[j]);
        const float r = f[j] - bf2f(h[j]);           // exact (cancellation)
        l[j] = (u16)(__float_as_uint(r) >> 16);      // trunc to bf16
    }
    ((ushort4*)Xh)[tid] = *(ushort4*)h;
    ((ushort4*)Xl)[tid] = *(ushort4*)l;
}

// ---------------- decomposed GEMM: C = (Xh+Xl)·Wd^T + bias ----------------

__global__ __launch_bounds__(256)
void gemm_q4(const u16* __restrict__ Xh, const u16* __restrict__ Xl,
             const u16* __restrict__ Wd, const float* __restrict__ Bi,
             float* __restrict__ C, int M, int N, int K)
{
    __shared__ __align__(16) u16 sAh[BM * BK];
    __shared__ __align__(16) u16 sAl[BM * BK];
    __shared__ __align__(16) u16 sB[BN * BK];

    const int nbx = N / BN;
    // bijective XCD swizzle (nwg % 8 == 0 here: 1024 blocks)
    const int nwg = gridDim.x;
    const int cpx = nwg >> 3;
    const int bid = blockIdx.x;
    const int swz = (bid & 7) * cpx + (bid >> 3);
    const int bx = swz % nbx, by = swz / nbx;
    const int brow = by * BM, bcol = bx * BN;

    const int t = threadIdx.x;
    const int lane = t & 63;
    const int wid = t >> 6;
    const int wr = wid >> 1, wc = wid & 1;
    const int fr = lane & 15;
    const int kslot = lane >> 4;          // 0..3, byte offset kslot*16 in 64B row

    // staging: linear idx16 = p*256 + t ; row = idx16>>2 ; slot = idx16&3
    const int r0 = t >> 2, sl = t & 3;

    f32x4 acc[4][4];
    #pragma unroll
    for (int m = 0; m < 4; ++m)
        #pragma unroll
        for (int n = 0; n < 4; ++n) acc[m][n] = (f32x4)0.f;

#define GLDS(gptr, ldsbase_bytes)                                                   \
    __builtin_amdgcn_global_load_lds(                                               \
        (const __attribute__((address_space(1))) u32*)(gptr),                       \
        (__attribute__((address_space(3))) u32*)(ldsbase_bytes), 16, 0, 0)

    const int nkt = K / BK;
    for (int kt = 0; kt < nkt; ++kt) {
        const int kc = kt * BK;
        // ---- stage 3 tiles, 2 passes each (wave-uniform LDS base + lane*16) ----
        {
            char* bAh = (char*)sAh + wid * 1024;
            char* bAl = (char*)sAl + wid * 1024;
            char* bB  = (char*)sB  + wid * 1024;
            const u16* gAh0 = Xh + (size_t)(brow + r0) * K + kc + sl * 8;
            const u16* gAh1 = Xh + (size_t)(brow + 64 + r0) * K + kc + sl * 8;
            const u16* gAl0 = Xl + (size_t)(brow + r0) * K + kc + sl * 8;
            const u16* gAl1 = Xl + (size_t)(brow + 64 + r0) * K + kc + sl * 8;
            const u16* gB0  = Wd + (size_t)(bcol + r0) * K + kc + sl * 8;
            const u16* gB1  = Wd + (size_t)(bcol + 64 + r0) * K + kc + sl * 8;
            GLDS(gAh0, bAh);
            GLDS(gAh1, bAh + 4096);
            GLDS(gAl0, bAl);
            GLDS(gAl1, bAl + 4096);
            GLDS(gB0,  bB);
            GLDS(gB1,  bB + 4096);
        }
        __syncthreads();

        // ---- fragments ----
        short8 ah[4], al[4], b[4];
        #pragma unroll
        for (int m = 0; m < 4; ++m) {
            const int row = wr * 64 + m * 16 + fr;
            ah[m] = *(const short8*)&sAh[row * BK + kslot * 8];
            al[m] = *(const short8*)&sAl[row * BK + kslot * 8];
        }
        #pragma unroll
        for (int n = 0; n < 4; ++n) {
            const int row = wc * 64 + n * 16 + fr;
            b[n] = *(const short8*)&sB[row * BK + kslot * 8];
        }
        #pragma unroll
        for (int m = 0; m < 4; ++m)
            #pragma unroll
            for (int n = 0; n < 4; ++n) {
                acc[m][n] = __builtin_amdgcn_mfma_f32_16x16x32_bf16(ah[m], b[n], acc[m][n], 0, 0, 0);
                acc[m][n] = __builtin_amdgcn_mfma_f32_16x16x32_bf16(al[m], b[n], acc[m][n], 0, 0, 0);
            }
        __syncthreads();
    }

    // ---- epilogue (verified layout: col=lane&15, row=(lane>>4)*4+i) ----
    const int row4 = (lane >> 4) << 2;
    const int col = lane & 15;
    #pragma unroll
    for (int n = 0; n < 4; ++n) {
        const int gc = bcol + wc * 64 + n * 16 + col;
        const float bb = Bi[gc];
        #pragma unroll
        for (int m = 0; m < 4; ++m) {
            const int gr = brow + wr * 64 + m * 16 + row4;
            #pragma unroll
            for (int i = 0; i < 4; ++i)
                C[(size_t)(gr + i) * N + gc] = acc[m][n][i] + bb;
        }
    }
#undef GLDS
}

// ---------------- fused fallback (round-1 kernel, proven) ----------------

__global__ __launch_bounds__(256, 2)
void q4_gemm_fused(const float* __restrict__ X, const int* __restrict__ WP,
                   const float* __restrict__ S, const float* __restrict__ Z,
                   const float* __restrict__ Bi, float* __restrict__ C,
                   int M, int N, int K, int NG)
{
    __shared__ __align__(16) u16 sa_hi[BM][LDP];
    __shared__ __align__(16) u16 sa_lo[BM][LDP];
    __shared__ __align__(16) u16 sb_hi[BN][LDP];
    __shared__ __align__(16) u16 sb_lo[BN][LDP];

    const int nbx = N / BN;
    const int bx = blockIdx.x % nbx;
    const int by = blockIdx.x / nbx;
    const int brow = by * BM, bcol = bx * BN;

    const int t = threadIdx.x;
    const int lane = t & 63;
    const int wid = t >> 6;
    const int wr = wid >> 1, wc = wid & 1;
    const int xc4 = t & 7, xr0 = t >> 3;
    const int wrow = t >> 1, whalf = t & 1;
    const int Kh = K >> 1;

    f32x4 acc[4][4];
    #pragma unroll
    for (int m = 0; m < 4; ++m)
        #pragma unroll
        for (int n = 0; n < 4; ++n) acc[m][n] = (f32x4)0.f;

    const int fr = lane & 15;
    const int k8 = (lane >> 4) << 3;

    const int nkt = K / BK;
    for (int kt = 0; kt < nkt; ++kt) {
        #pragma unroll
        for (int p = 0; p < 4; ++p) {
            const int r = xr0 + p * 32;
            const float4 v = *(const float4*)&X[(size_t)(brow + r) * K + kt * BK + xc4 * 4];
            u16 h[4], l[4];
            const float f[4] = {v.x, v.y, v.z, v.w};
            #pragma unroll
            for (int j = 0; j < 4; ++j) {
                h[j] = f2bf_rne(f[j]);
                l[j] = f2bf_rne(f[j] - bf2f(h[j]));
            }
            *(ushort4*)&sa_hi[r][xc4 * 4] = *(ushort4*)h;
            *(ushort4*)&sa_lo[r][xc4 * 4] = *(ushort4*)l;
        }
        {
            const int n = bcol + wrow;
            const float s = S[n * NG + kt];
            const float z = Z[n * NG + kt];
            const float nzs = -z * s;
            const int4* pp = (const int4*)&WP[(size_t)n * Kh + kt * 16 + whalf * 8];
            const int4 p0 = pp[0], p1 = pp[1];
            const int vals[8] = {p0.x, p0.y, p0.z, p0.w, p1.x, p1.y, p1.z, p1.w};
            __align__(16) u16 hi[16], lo[16];
            #pragma unroll
            for (int j = 0; j < 8; ++j) {
                const int v = vals[j];
                const float w0 = fmaf((float)(v & 15), s, nzs);
                const float w1 = fmaf((float)((v >> 4) & 15), s, nzs);
                hi[2 * j] = f2bf_rne(w0); lo[2 * j] = f2bf_rne(w0 - bf2f(hi[2 * j]));
                hi[2 * j + 1] = f2bf_rne(w1); lo[2 * j + 1] = f2bf_rne(w1 - bf2f(hi[2 * j + 1]));
            }
            #pragma unroll
            for (int q = 0; q < 4; ++q) {
                *(ushort4*)&sb_hi[wrow][whalf * 16 + q * 4] = *(ushort4*)&hi[q * 4];
                *(ushort4*)&sb_lo[wrow][whalf * 16 + q * 4] = *(ushort4*)&lo[q * 4];
            }
        }
        __syncthreads();

        short8 ah[4], al[4], bh[4], bl[4];
        #pragma unroll
        for (int m = 0; m < 4; ++m) {
            ah[m] = *(const short8*)&sa_hi[wr * 64 + m * 16 + fr][k8];
            al[m] = *(const short8*)&sa_lo[wr * 64 + m * 16 + fr][k8];
        }
        #pragma unroll
        for (int n = 0; n < 4; ++n) {
            bh[n] = *(const short8*)&sb_hi[wc * 64 + n * 16 + fr][k8];
            bl[n] = *(const short8*)&sb_lo[wc * 64 + n * 16 + fr][k8];
        }
        #pragma unroll
        for (int m = 0; m < 4; ++m)
            #pragma unroll
            for (int n = 0; n < 4; ++n) {
                acc[m][n] = __builtin_amdgcn_mfma_f32_16x16x32_bf16(ah[m], bh[n], acc[m][n], 0, 0, 0);
                acc[m][n] = __builtin_amdgcn_mfma_f32_16x16x32_bf16(ah[m], bl[n], acc[m][n], 0, 0, 0);
                acc[m][n] = __builtin_amdgcn_mfma_f32_16x16x32_bf16(al[m], bh[n], acc[m][n], 0, 0, 0);
            }
        __syncthreads();
    }

    const int row4 = (lane >> 4) << 2;
    const int col = lane & 15;
    #pragma unroll
    for (int n = 0; n < 4; ++n) {
        const int gc = bcol + wc * 64 + n * 16 + col;
        const float bb = Bi[gc];
        #pragma unroll
        for (int m = 0; m < 4; ++m) {
            const int gr = brow + wr * 64 + m * 16 + row4;
            #pragma unroll
            for (int i = 0; i < 4; ++i)
                C[(size_t)(gr + i) * N + gc] = acc[m][n][i] + bb;
        }
    }
}

// ---------------- launch ----------------

extern "C" void kernel_launch(void* const* d_in, const int* in_sizes, int n_in,
                              void* d_out, int out_size, void* d_ws, size_t ws_size,
                              hipStream_t stream)
{
    const float* X  = (const float*)d_in[0];
    const int*   WP = (const int*)d_in[1];
    const float* S  = (const float*)d_in[2];
    const float* Z  = (const float*)d_in[3];
    const float* Bi = (const float*)d_in[4];
    float* C = (float*)d_out;

    const int O  = in_sizes[4];            // 4096
    const int NG = in_sizes[2] / O;        // 128
    const int K  = NG * 32;                // 4096
    const int M  = in_sizes[0] / K;        // 4096

    const size_t needW = (size_t)O * K * 2;
    const size_t needX = (size_t)M * K * 2;
    const size_t need = needW + 2 * needX;

    if (ws_size >= need) {
        u16* Wd = (u16*)d_ws;
        u16* Xhp = Wd + (size_t)O * K;
        u16* Xlp = Xhp + (size_t)M * K;

        prep_w<<<(O * NG) / 256, 256, 0, stream>>>(WP, S, Z, Wd, NG);
        prep_x<<<(M * K / 4) / 256, 256, 0, stream>>>(X, Xhp, Xlp);

        dim3 grid((M / BM) * (O / BN));
        gemm_q4<<<grid, 256, 0, stream>>>(Xhp, Xlp, Wd, Bi, C, M, O, K);
    } else {
        dim3 grid((M / BM) * (O / BN));
        q4_gemm_fused<<<grid, 256, 0, stream>>>(X, WP, S, Z, Bi, C, M, O, K, NG);
    }
}

// Round 4
// 373.185 us; speedup vs baseline: 1.6289x; 1.1972x over previous
//
#include <hip/hip_runtime.h>

typedef __attribute__((ext_vector_type(8))) short short8;
typedef __attribute__((ext_vector_type(4))) float f32x4;
typedef unsigned short u16;
typedef unsigned int u32;

#define BM 128
#define BN 128
#define BK 32
#define LDP 40   // fused-fallback padded stride

__device__ __forceinline__ u16 f2bf_rne(float f) {
    u32 u = __float_as_uint(f);
    return (u16)((u + 0x7fffu + ((u >> 16) & 1u)) >> 16);
}
__device__ __forceinline__ float bf2f(u16 b) { return __uint_as_float(((u32)b) << 16); }

// ---------------- prep kernels (decomposed path) ----------------

// One thread per (o, group): unpack 32 nibbles, dequant, write 32 bf16 (64 B).
__global__ __launch_bounds__(256)
void prep_w(const int* __restrict__ WP, const float* __restrict__ S,
            const float* __restrict__ Z, u16* __restrict__ Wd, int NG)
{
    const int tid = blockIdx.x * blockDim.x + threadIdx.x;
    const int o = tid / NG, g = tid % NG;
    const float s = S[o * NG + g];
    const float nzs = -Z[o * NG + g] * s;
    const int4* p = (const int4*)&WP[(size_t)(o * NG + g) * 16];
    __align__(16) u16 out[32];
    #pragma unroll
    for (int q4 = 0; q4 < 4; ++q4) {
        const int4 v4 = p[q4];
        const int vv[4] = {v4.x, v4.y, v4.z, v4.w};
        #pragma unroll
        for (int j = 0; j < 4; ++j) {
            const int v = vv[j];
            out[(q4 * 4 + j) * 2]     = f2bf_rne(fmaf((float)(v & 15), s, nzs));
            out[(q4 * 4 + j) * 2 + 1] = f2bf_rne(fmaf((float)((v >> 4) & 15), s, nzs));
        }
    }
    uint4* dst = (uint4*)&Wd[(size_t)tid * 32];
    const uint4* src = (const uint4*)out;
    dst[0] = src[0]; dst[1] = src[1]; dst[2] = src[2]; dst[3] = src[3];
}

// One thread per 8 floats: X -> bf16 (RNE).
__global__ __launch_bounds__(256)
void prep_x(const float* __restrict__ X, u16* __restrict__ Xh)
{
    const int tid = blockIdx.x * blockDim.x + threadIdx.x;
    const float4 v0 = ((const float4*)X)[tid * 2];
    const float4 v1 = ((const float4*)X)[tid * 2 + 1];
    const float f[8] = {v0.x, v0.y, v0.z, v0.w, v1.x, v1.y, v1.z, v1.w};
    __align__(16) u16 h[8];
    #pragma unroll
    for (int j = 0; j < 8; ++j) h[j] = f2bf_rne(f[j]);
    ((uint4*)Xh)[tid] = *(uint4*)h;
}

// ---------------- decomposed GEMM: C = Xh·Wd^T + bias (1-term bf16) ----------------

__global__ __launch_bounds__(256)
void gemm_q4(const u16* __restrict__ Xh, const u16* __restrict__ Wd,
             const float* __restrict__ Bi, float* __restrict__ C,
             int M, int N, int K)
{
    __shared__ __align__(16) u16 sA[BM * BK];
    __shared__ __align__(16) u16 sB[BN * BK];

    const int nbx = N / BN;
    // bijective XCD swizzle (nwg = 1024, %8 == 0)
    const int nwg = gridDim.x;
    const int cpx = nwg >> 3;
    const int bid = blockIdx.x;
    const int swz = (bid & 7) * cpx + (bid >> 3);
    const int bx = swz % nbx, by = swz / nbx;
    const int brow = by * BM, bcol = bx * BN;

    const int t = threadIdx.x;
    const int lane = t & 63;
    const int wid = t >> 6;
    const int wr = wid >> 1, wc = wid & 1;
    const int fr = lane & 15;
    const int kslot = lane >> 4;          // 0..3 -> k offset kslot*8 elements

    // staging: thread t covers 16B chunk t of the 8KB tile; row = t>>2, slot = t&3
    const int r0 = t >> 2, sl = t & 3;

    f32x4 acc[4][4];
    #pragma unroll
    for (int m = 0; m < 4; ++m)
        #pragma unroll
        for (int n = 0; n < 4; ++n) acc[m][n] = (f32x4)0.f;

#define GLDS(gptr, ldsbase_bytes)                                                   \
    __builtin_amdgcn_global_load_lds(                                               \
        (const __attribute__((address_space(1))) u32*)(gptr),                       \
        (__attribute__((address_space(3))) u32*)(ldsbase_bytes), 16, 0, 0)

    const int nkt = K / BK;
    for (int kt = 0; kt < nkt; ++kt) {
        const int kc = kt * BK;
        {
            char* bA = (char*)sA + wid * 1024;
            char* bB = (char*)sB + wid * 1024;
            const u16* gA0 = Xh + (size_t)(brow + r0) * K + kc + sl * 8;
            const u16* gA1 = Xh + (size_t)(brow + 64 + r0) * K + kc + sl * 8;
            const u16* gB0 = Wd + (size_t)(bcol + r0) * K + kc + sl * 8;
            const u16* gB1 = Wd + (size_t)(bcol + 64 + r0) * K + kc + sl * 8;
            GLDS(gA0, bA);
            GLDS(gA1, bA + 4096);
            GLDS(gB0, bB);
            GLDS(gB1, bB + 4096);
        }
        __syncthreads();

        short8 a[4], b[4];
        #pragma unroll
        for (int m = 0; m < 4; ++m) {
            const int row = wr * 64 + m * 16 + fr;
            a[m] = *(const short8*)&sA[row * BK + kslot * 8];
        }
        #pragma unroll
        for (int n = 0; n < 4; ++n) {
            const int row = wc * 64 + n * 16 + fr;
            b[n] = *(const short8*)&sB[row * BK + kslot * 8];
        }
        #pragma unroll
        for (int m = 0; m < 4; ++m)
            #pragma unroll
            for (int n = 0; n < 4; ++n)
                acc[m][n] = __builtin_amdgcn_mfma_f32_16x16x32_bf16(a[m], b[n], acc[m][n], 0, 0, 0);
        __syncthreads();
    }

    // epilogue (verified layout: col=lane&15, row=(lane>>4)*4+i)
    const int row4 = (lane >> 4) << 2;
    const int col = lane & 15;
    #pragma unroll
    for (int n = 0; n < 4; ++n) {
        const int gc = bcol + wc * 64 + n * 16 + col;
        const float bb = Bi[gc];
        #pragma unroll
        for (int m = 0; m < 4; ++m) {
            const int gr = brow + wr * 64 + m * 16 + row4;
            #pragma unroll
            for (int i = 0; i < 4; ++i)
                C[(size_t)(gr + i) * N + gc] = acc[m][n][i] + bb;
        }
    }
#undef GLDS
}

// ---------------- fused fallback (round-1 kernel, proven) ----------------

__global__ __launch_bounds__(256, 2)
void q4_gemm_fused(const float* __restrict__ X, const int* __restrict__ WP,
                   const float* __restrict__ S, const float* __restrict__ Z,
                   const float* __restrict__ Bi, float* __restrict__ C,
                   int M, int N, int K, int NG)
{
    __shared__ __align__(16) u16 sa_hi[BM][LDP];
    __shared__ __align__(16) u16 sa_lo[BM][LDP];
    __shared__ __align__(16) u16 sb_hi[BN][LDP];
    __shared__ __align__(16) u16 sb_lo[BN][LDP];

    const int nbx = N / BN;
    const int bx = blockIdx.x % nbx;
    const int by = blockIdx.x / nbx;
    const int brow = by * BM, bcol = bx * BN;

    const int t = threadIdx.x;
    const int lane = t & 63;
    const int wid = t >> 6;
    const int wr = wid >> 1, wc = wid & 1;
    const int xc4 = t & 7, xr0 = t >> 3;
    const int wrow = t >> 1, whalf = t & 1;
    const int Kh = K >> 1;

    f32x4 acc[4][4];
    #pragma unroll
    for (int m = 0; m < 4; ++m)
        #pragma unroll
        for (int n = 0; n < 4; ++n) acc[m][n] = (f32x4)0.f;

    const int fr = lane & 15;
    const int k8 = (lane >> 4) << 3;

    const int nkt = K / BK;
    for (int kt = 0; kt < nkt; ++kt) {
        #pragma unroll
        for (int p = 0; p < 4; ++p) {
            const int r = xr0 + p * 32;
            const float4 v = *(const float4*)&X[(size_t)(brow + r) * K + kt * BK + xc4 * 4];
            u16 h[4], l[4];
            const float f[4] = {v.x, v.y, v.z, v.w};
            #pragma unroll
            for (int j = 0; j < 4; ++j) {
                h[j] = f2bf_rne(f[j]);
                l[j] = f2bf_rne(f[j] - bf2f(h[j]));
            }
            *(ushort4*)&sa_hi[r][xc4 * 4] = *(ushort4*)h;
            *(ushort4*)&sa_lo[r][xc4 * 4] = *(ushort4*)l;
        }
        {
            const int n = bcol + wrow;
            const float s = S[n * NG + kt];
            const float z = Z[n * NG + kt];
            const float nzs = -z * s;
            const int4* pp = (const int4*)&WP[(size_t)n * Kh + kt * 16 + whalf * 8];
            const int4 p0 = pp[0], p1 = pp[1];
            const int vals[8] = {p0.x, p0.y, p0.z, p0.w, p1.x, p1.y, p1.z, p1.w};
            __align__(16) u16 hi[16], lo[16];
            #pragma unroll
            for (int j = 0; j < 8; ++j) {
                const int v = vals[j];
                const float w0 = fmaf((float)(v & 15), s, nzs);
                const float w1 = fmaf((float)((v >> 4) & 15), s, nzs);
                hi[2 * j] = f2bf_rne(w0); lo[2 * j] = f2bf_rne(w0 - bf2f(hi[2 * j]));
                hi[2 * j + 1] = f2bf_rne(w1); lo[2 * j + 1] = f2bf_rne(w1 - bf2f(hi[2 * j + 1]));
            }
            #pragma unroll
            for (int q = 0; q < 4; ++q) {
                *(ushort4*)&sb_hi[wrow][whalf * 16 + q * 4] = *(ushort4*)&hi[q * 4];
                *(ushort4*)&sb_lo[wrow][whalf * 16 + q * 4] = *(ushort4*)&lo[q * 4];
            }
        }
        __syncthreads();

        short8 ah[4], al[4], bh[4], bl[4];
        #pragma unroll
        for (int m = 0; m < 4; ++m) {
            ah[m] = *(const short8*)&sa_hi[wr * 64 + m * 16 + fr][k8];
            al[m] = *(const short8*)&sa_lo[wr * 64 + m * 16 + fr][k8];
        }
        #pragma unroll
        for (int n = 0; n < 4; ++n) {
            bh[n] = *(const short8*)&sb_hi[wc * 64 + n * 16 + fr][k8];
            bl[n] = *(const short8*)&sb_lo[wc * 64 + n * 16 + fr][k8];
        }
        #pragma unroll
        for (int m = 0; m < 4; ++m)
            #pragma unroll
            for (int n = 0; n < 4; ++n) {
                acc[m][n] = __builtin_amdgcn_mfma_f32_16x16x32_bf16(ah[m], bh[n], acc[m][n], 0, 0, 0);
                acc[m][n] = __builtin_amdgcn_mfma_f32_16x16x32_bf16(ah[m], bl[n], acc[m][n], 0, 0, 0);
                acc[m][n] = __builtin_amdgcn_mfma_f32_16x16x32_bf16(al[m], bh[n], acc[m][n], 0, 0, 0);
            }
        __syncthreads();
    }

    const int row4 = (lane >> 4) << 2;
    const int col = lane & 15;
    #pragma unroll
    for (int n = 0; n < 4; ++n) {
        const int gc = bcol + wc * 64 + n * 16 + col;
        const float bb = Bi[gc];
        #pragma unroll
        for (int m = 0; m < 4; ++m) {
            const int gr = brow + wr * 64 + m * 16 + row4;
            #pragma unroll
            for (int i = 0; i < 4; ++i)
                C[(size_t)(gr + i) * N + gc] = acc[m][n][i] + bb;
        }
    }
}

// ---------------- launch ----------------

extern "C" void kernel_launch(void* const* d_in, const int* in_sizes, int n_in,
                              void* d_out, int out_size, void* d_ws, size_t ws_size,
                              hipStream_t stream)
{
    const float* X  = (const float*)d_in[0];
    const int*   WP = (const int*)d_in[1];
    const float* S  = (const float*)d_in[2];
    const float* Z  = (const float*)d_in[3];
    const float* Bi = (const float*)d_in[4];
    float* C = (float*)d_out;

    const int O  = in_sizes[4];            // 4096
    const int NG = in_sizes[2] / O;        // 128
    const int K  = NG * 32;                // 4096
    const int M  = in_sizes[0] / K;        // 4096

    const size_t needW = (size_t)O * K * 2;
    const size_t needX = (size_t)M * K * 2;
    const size_t need = needW + needX;

    if (ws_size >= need) {
        u16* Wd  = (u16*)d_ws;
        u16* Xhp = Wd + (size_t)O * K;

        prep_w<<<(O * NG) / 256, 256, 0, stream>>>(WP, S, Z, Wd, NG);
        prep_x<<<(M * K / 8) / 256, 256, 0, stream>>>(X, Xhp);

        dim3 grid((M / BM) * (O / BN));
        gemm_q4<<<grid, 256, 0, stream>>>(Xhp, Wd, Bi, C, M, O, K);
    } else {
        dim3 grid((M / BM) * (O / BN));
        q4_gemm_fused<<<grid, 256, 0, stream>>>(X, WP, S, Z, Bi, C, M, O, K, NG);
    }
}

// Round 6
// 307.149 us; speedup vs baseline: 1.9791x; 1.2150x over previous
//
#include <hip/hip_runtime.h>

typedef __attribute__((ext_vector_type(8))) short short8;
typedef __attribute__((ext_vector_type(4))) float f32x4;
typedef unsigned short u16;
typedef unsigned int u32;

#define BM 256
#define BN 256
#define BK 32
#define NBUF 4
#define LDP 40   // fused-fallback padded stride

__device__ __forceinline__ u16 f2bf_rne(float f) {
    u32 u = __float_as_uint(f);
    return (u16)((u + 0x7fffu + ((u >> 16) & 1u)) >> 16);
}
__device__ __forceinline__ float bf2f(u16 b) { return __uint_as_float(((u32)b) << 16); }

// ---------------- prep kernels (unchanged, proven) ----------------

__global__ __launch_bounds__(256)
void prep_w(const int* __restrict__ WP, const float* __restrict__ S,
            const float* __restrict__ Z, u16* __restrict__ Wd, int NG)
{
    const int tid = blockIdx.x * blockDim.x + threadIdx.x;
    const int o = tid / NG, g = tid % NG;
    const float s = S[o * NG + g];
    const float nzs = -Z[o * NG + g] * s;
    const int4* p = (const int4*)&WP[(size_t)(o * NG + g) * 16];
    __align__(16) u16 out[32];
    #pragma unroll
    for (int q4 = 0; q4 < 4; ++q4) {
        const int4 v4 = p[q4];
        const int vv[4] = {v4.x, v4.y, v4.z, v4.w};
        #pragma unroll
        for (int j = 0; j < 4; ++j) {
            const int v = vv[j];
            out[(q4 * 4 + j) * 2]     = f2bf_rne(fmaf((float)(v & 15), s, nzs));
            out[(q4 * 4 + j) * 2 + 1] = f2bf_rne(fmaf((float)((v >> 4) & 15), s, nzs));
        }
    }
    uint4* dst = (uint4*)&Wd[(size_t)tid * 32];
    const uint4* src = (const uint4*)out;
    dst[0] = src[0]; dst[1] = src[1]; dst[2] = src[2]; dst[3] = src[3];
}

__global__ __launch_bounds__(256)
void prep_x(const float* __restrict__ X, u16* __restrict__ Xh)
{
    const int tid = blockIdx.x * blockDim.x + threadIdx.x;
    const float4 v0 = ((const float4*)X)[tid * 2];
    const float4 v1 = ((const float4*)X)[tid * 2 + 1];
    const float f[8] = {v0.x, v0.y, v0.z, v0.w, v1.x, v1.y, v1.z, v1.w};
    __align__(16) u16 h[8];
    #pragma unroll
    for (int j = 0; j < 8; ++j) h[j] = f2bf_rne(f[j]);
    ((uint4*)Xh)[tid] = *(uint4*)h;
}

// ------- deep-pipelined 256x256 GEMM: C = Xh·Wd^T + bias -------
// 512 thr (8 waves: 2m x 4n), BK=32, 4-deep LDS ring, counted vmcnt,
// XOR-swizzled LDS (slot = chunk ^ ((row>>2)&3) -> 2-way/free reads),
// setprio around MFMA cluster, bijective XCD swizzle.

#define GLDS(gptr, ldsbase)                                                         \
    __builtin_amdgcn_global_load_lds(                                               \
        (const __attribute__((address_space(1))) u32*)(gptr),                       \
        (__attribute__((address_space(3))) u32*)(ldsbase), 16, 0, 0)

__global__ __launch_bounds__(512, 2)
void gemm_q4(const u16* __restrict__ Xh, const u16* __restrict__ Wd,
             const float* __restrict__ Bi, float* __restrict__ C,
             int M, int N, int K)
{
    // 4 ring buffers x 16KB per operand = 128 KiB total
    __shared__ __align__(16) u16 sA[NBUF * 8192];
    __shared__ __align__(16) u16 sB[NBUF * 8192];

    const int nbx = N / BN;                  // 16
    const int nwg = gridDim.x;               // 256 (%8==0 -> simple bijective)
    const int cpx = nwg >> 3;
    const int bid = blockIdx.x;
    const int swz = (bid & 7) * cpx + (bid >> 3);
    const int bx = swz % nbx, by = swz / nbx;
    const int brow = by * BM, bcol = bx * BN;

    const int t = threadIdx.x;
    const int lane = t & 63;
    const int wid = t >> 6;                  // 0..7
    const int wr = wid >> 2;                 // 0..1  (128-row block)
    const int wcn = wid & 3;                 // 0..3  (64-col block)
    const int fr = lane & 15;
    // read-side swizzled slot: chunk = lane>>4, (row>>2)&3 = (lane>>2)&3
    // bank span = 16*(lane&1) + 4*((lane>>2)&3) -> 2 lanes/span = free
    const int ps8 = (((lane >> 4) ^ ((lane >> 2) & 3)) << 3);

    // ---- staging geometry: per tile, per operand: 2 gloads/wave ----
    // LDS linear byte o = g*8192(B) + wid*1024 + lane*16
    //   -> row r = g*128 + wid*16 + (lane>>2), phys slot = lane&3
    //   -> (row>>2)&3 = (lane>>4)&3  (wid*4 ≡ 0 mod 4)
    //   -> logical chunk = (lane&3) ^ ((lane>>4)&3)
    const int srow = wid * 16 + (lane >> 2);
    const int schunk = ((lane & 3) ^ ((lane >> 4) & 3)) * 8;   // element offset
    const u16* srcA0 = Xh + (size_t)(brow + srow) * K + schunk;
    const u16* srcA1 = Xh + (size_t)(brow + 128 + srow) * K + schunk;
    const u16* srcB0 = Wd + (size_t)(bcol + srow) * K + schunk;
    const u16* srcB1 = Wd + (size_t)(bcol + 128 + srow) * K + schunk;

    f32x4 acc[8][4];
    #pragma unroll
    for (int m = 0; m < 8; ++m)
        #pragma unroll
        for (int n = 0; n < 4; ++n) acc[m][n] = (f32x4)0.f;

    const int nkt = K / BK;                  // 128

#define STAGE(bufi, kt)                                                   \
    do {                                                                  \
        const size_t ko = (size_t)(kt) * BK;                              \
        char* baA = (char*)sA + (bufi) * 16384 + wid * 1024;              \
        char* baB = (char*)sB + (bufi) * 16384 + wid * 1024;              \
        GLDS(srcA0 + ko, baA);                                            \
        GLDS(srcA1 + ko, baA + 8192);                                     \
        GLDS(srcB0 + ko, baB);                                            \
        GLDS(srcB1 + ko, baB + 8192);                                     \
    } while (0)

    // ---- prologue: fill the 4-deep ring ----
    STAGE(0, 0);
    STAGE(1, 1);
    STAGE(2, 2);
    STAGE(3, 3);
    asm volatile("s_waitcnt vmcnt(12)" ::: "memory");   // tile 0 landed
    __builtin_amdgcn_s_barrier();

    for (int kt = 0; kt < nkt; ++kt) {
        const int cur = kt & 3;
        const u16* bufA = sA + cur * 8192;
        const u16* bufB = sB + cur * 8192;

        // ---- read all fragments of tile kt (swizzled addresses) ----
        short8 a[8], b[4];
        #pragma unroll
        for (int m = 0; m < 8; ++m) {
            const int row = wr * 128 + m * 16 + fr;
            a[m] = *(const short8*)&bufA[row * 32 + ps8];
        }
        #pragma unroll
        for (int n = 0; n < 4; ++n) {
            const int row = wcn * 64 + n * 16 + fr;
            b[n] = *(const short8*)&bufB[row * 32 + ps8];
        }

        // all waves' reads of buf[cur] retired -> safe to restage it
        asm volatile("s_waitcnt lgkmcnt(0)" ::: "memory");
        __builtin_amdgcn_s_barrier();

        if (kt + 4 < nkt) STAGE(cur, kt + 4);

        __builtin_amdgcn_s_setprio(1);
        #pragma unroll
        for (int m = 0; m < 8; ++m)
            #pragma unroll
            for (int n = 0; n < 4; ++n)
                acc[m][n] = __builtin_amdgcn_mfma_f32_16x16x32_bf16(a[m], b[n], acc[m][n], 0, 0, 0);
        __builtin_amdgcn_s_setprio(0);

        // counted vmcnt: keep 3 tiles (12 loads) in flight; step down in tail
        if (kt + 4 < nkt)      asm volatile("s_waitcnt vmcnt(12)" ::: "memory");
        else if (kt + 3 < nkt) asm volatile("s_waitcnt vmcnt(8)"  ::: "memory");
        else if (kt + 2 < nkt) asm volatile("s_waitcnt vmcnt(4)"  ::: "memory");
        else if (kt + 1 < nkt) asm volatile("s_waitcnt vmcnt(0)"  ::: "memory");
        __builtin_amdgcn_s_barrier();
    }

    // ---- epilogue: C = acc + bias (layout: col=lane&15, row=(lane>>4)*4+i) ----
    const int row4 = (lane >> 4) << 2;
    const int col = lane & 15;
    #pragma unroll
    for (int n = 0; n < 4; ++n) {
        const int gc = bcol + wcn * 64 + n * 16 + col;
        const float bb = Bi[gc];
        #pragma unroll
        for (int m = 0; m < 8; ++m) {
            const int gr = brow + wr * 128 + m * 16 + row4;
            #pragma unroll
            for (int i = 0; i < 4; ++i)
                C[(size_t)(gr + i) * N + gc] = acc[m][n][i] + bb;
        }
    }
}
#undef STAGE
#undef GLDS

// ---------------- fused fallback (round-1 kernel, proven) ----------------

__global__ __launch_bounds__(256, 2)
void q4_gemm_fused(const float* __restrict__ X, const int* __restrict__ WP,
                   const float* __restrict__ S, const float* __restrict__ Z,
                   const float* __restrict__ Bi, float* __restrict__ C,
                   int M, int N, int K, int NG)
{
    __shared__ __align__(16) u16 sa_hi[128][LDP];
    __shared__ __align__(16) u16 sa_lo[128][LDP];
    __shared__ __align__(16) u16 sb_hi[128][LDP];
    __shared__ __align__(16) u16 sb_lo[128][LDP];

    const int nbx = N / 128;
    const int bx = blockIdx.x % nbx;
    const int by = blockIdx.x / nbx;
    const int brow = by * 128, bcol = bx * 128;

    const int t = threadIdx.x;
    const int lane = t & 63;
    const int wid = t >> 6;
    const int wr = wid >> 1, wc = wid & 1;
    const int xc4 = t & 7, xr0 = t >> 3;
    const int wrow = t >> 1, whalf = t & 1;
    const int Kh = K >> 1;

    f32x4 acc[4][4];
    #pragma unroll
    for (int m = 0; m < 4; ++m)
        #pragma unroll
        for (int n = 0; n < 4; ++n) acc[m][n] = (f32x4)0.f;

    const int fr = lane & 15;
    const int k8 = (lane >> 4) << 3;

    const int nkt = K / 32;
    for (int kt = 0; kt < nkt; ++kt) {
        #pragma unroll
        for (int p = 0; p < 4; ++p) {
            const int r = xr0 + p * 32;
            const float4 v = *(const float4*)&X[(size_t)(brow + r) * K + kt * 32 + xc4 * 4];
            u16 h[4], l[4];
            const float f[4] = {v.x, v.y, v.z, v.w};
            #pragma unroll
            for (int j = 0; j < 4; ++j) {
                h[j] = f2bf_rne(f[j]);
                l[j] = f2bf_rne(f[j] - bf2f(h[j]));
            }
            *(ushort4*)&sa_hi[r][xc4 * 4] = *(ushort4*)h;
            *(ushort4*)&sa_lo[r][xc4 * 4] = *(ushort4*)l;
        }
        {
            const int n = bcol + wrow;
            const float s = S[n * NG + kt];
            const float z = Z[n * NG + kt];
            const float nzs = -z * s;
            const int4* pp = (const int4*)&WP[(size_t)n * Kh + kt * 16 + whalf * 8];
            const int4 p0 = pp[0], p1 = pp[1];
            const int vals[8] = {p0.x, p0.y, p0.z, p0.w, p1.x, p1.y, p1.z, p1.w};
            __align__(16) u16 hi[16], lo[16];
            #pragma unroll
            for (int j = 0; j < 8; ++j) {
                const int v = vals[j];
                const float w0 = fmaf((float)(v & 15), s, nzs);
                const float w1 = fmaf((float)((v >> 4) & 15), s, nzs);
                hi[2 * j] = f2bf_rne(w0); lo[2 * j] = f2bf_rne(w0 - bf2f(hi[2 * j]));
                hi[2 * j + 1] = f2bf_rne(w1); lo[2 * j + 1] = f2bf_rne(w1 - bf2f(hi[2 * j + 1]));
            }
            #pragma unroll
            for (int q = 0; q < 4; ++q) {
                *(ushort4*)&sb_hi[wrow][whalf * 16 + q * 4] = *(ushort4*)&hi[q * 4];
                *(ushort4*)&sb_lo[wrow][whalf * 16 + q * 4] = *(ushort4*)&lo[q * 4];
            }
        }
        __syncthreads();

        short8 ah[4], al[4], bh[4], bl[4];
        #pragma unroll
        for (int m = 0; m < 4; ++m) {
            ah[m] = *(const short8*)&sa_hi[wr * 64 + m * 16 + fr][k8];
            al[m] = *(const short8*)&sa_lo[wr * 64 + m * 16 + fr][k8];
        }
        #pragma unroll
        for (int n = 0; n < 4; ++n) {
            bh[n] = *(const short8*)&sb_hi[wc * 64 + n * 16 + fr][k8];
            bl[n] = *(const short8*)&sb_lo[wc * 64 + n * 16 + fr][k8];
        }
        #pragma unroll
        for (int m = 0; m < 4; ++m)
            #pragma unroll
            for (int n = 0; n < 4; ++n) {
                acc[m][n] = __builtin_amdgcn_mfma_f32_16x16x32_bf16(ah[m], bh[n], acc[m][n], 0, 0, 0);
                acc[m][n] = __builtin_amdgcn_mfma_f32_16x16x32_bf16(ah[m], bl[n], acc[m][n], 0, 0, 0);
                acc[m][n] = __builtin_amdgcn_mfma_f32_16x16x32_bf16(al[m], bh[n], acc[m][n], 0, 0, 0);
            }
        __syncthreads();
    }

    const int row4 = (lane >> 4) << 2;
    const int col = lane & 15;
    #pragma unroll
    for (int n = 0; n < 4; ++n) {
        const int gc = bcol + wc * 64 + n * 16 + col;
        const float bb = Bi[gc];
        #pragma unroll
        for (int m = 0; m < 4; ++m) {
            const int gr = brow + wr * 64 + m * 16 + row4;
            #pragma unroll
            for (int i = 0; i < 4; ++i)
                C[(size_t)(gr + i) * N + gc] = acc[m][n][i] + bb;
        }
    }
}

// ---------------- launch ----------------

extern "C" void kernel_launch(void* const* d_in, const int* in_sizes, int n_in,
                              void* d_out, int out_size, void* d_ws, size_t ws_size,
                              hipStream_t stream)
{
    const float* X  = (const float*)d_in[0];
    const int*   WP = (const int*)d_in[1];
    const float* S  = (const float*)d_in[2];
    const float* Z  = (const float*)d_in[3];
    const float* Bi = (const float*)d_in[4];
    float* C = (float*)d_out;

    const int O  = in_sizes[4];            // 4096
    const int NG = in_sizes[2] / O;        // 128
    const int K  = NG * 32;                // 4096
    const int M  = in_sizes[0] / K;        // 4096

    const size_t needW = (size_t)O * K * 2;
    const size_t needX = (size_t)M * K * 2;
    const size_t need = needW + needX;

    if (ws_size >= need && (M % BM) == 0 && (O % BN) == 0) {
        u16* Wd  = (u16*)d_ws;
        u16* Xhp = Wd + (size_t)O * K;

        prep_w<<<(O * NG) / 256, 256, 0, stream>>>(WP, S, Z, Wd, NG);
        prep_x<<<(M * K / 8) / 256, 256, 0, stream>>>(X, Xhp);

        dim3 grid((M / BM) * (O / BN));
        gemm_q4<<<grid, 512, 0, stream>>>(Xhp, Wd, Bi, C, M, O, K);
    } else {
        dim3 grid((M / 128) * (O / 128));
        q4_gemm_fused<<<grid, 256, 0, stream>>>(X, WP, S, Z, Bi, C, M, O, K, NG);
    }
}